// Round 1
// baseline (825.865 us; speedup 1.0000x reference)
//
#include <hip/hip_runtime.h>

// CharRNN fused kernel: B=256, L=1024, V=40, H=128.
// One block per batch row (grid 256 = 1 block/CU), 256 threads = 4 waves.
// Thread (j = tid&127, half = tid>>7): split-K=2 over the H=128 dot product
// so all 4 SIMDs issue FMAs -> per-step dot = 64 FMA/thread.
// Wh slice lives in registers (64 VGPR/thread). h state ping-pongs in LDS.
// Logits fused via 32-step h ring + burst (5 full dots/thread, no reduction).

#define BB 256
#define LL 1024
#define VV 40
#define HH 128
#define WIN 32
#define RSTR 132   // padded stride (floats) for ring / Wo: breaks 40-way bank conflict

__global__ __launch_bounds__(256) void rnn_fused(
    const int*   __restrict__ x,       // [B,L]
    const float* __restrict__ hidden,  // [B,H]
    const float* __restrict__ emb,     // [V,H]
    const float* __restrict__ Wh,      // [H,H]
    const float* __restrict__ Wo,      // [V,H]
    const float* __restrict__ b_h,     // [H]
    const float* __restrict__ b_y,     // [V]
    float*       __restrict__ out)     // [B*L*V logits][B*H final_hidden]
{
    __shared__ float emb_s[VV * HH];     // 20 KB
    __shared__ float wo_s[VV * RSTR];    // 21.1 KB
    __shared__ float ring[WIN * RSTR];   // 16.9 KB
    __shared__ float hbuf[2 * HH];       // 1 KB
    __shared__ float partial[HH];        // 0.5 KB
    __shared__ float bys[VV];
    __shared__ int   xbuf[LL];           // 4 KB
    // total ~63.5 KB static LDS (limit 64 KB)

    const int tid  = threadIdx.x;
    const int b    = blockIdx.x;
    const int j    = tid & (HH - 1);
    const int half = tid >> 7;

    // ---- stage x sequence ----
    {
        const int4* xg = (const int4*)(x + (size_t)b * LL);
        int4* xs = (int4*)xbuf;
        for (int i = tid; i < LL / 4; i += 256) xs[i] = xg[i];
    }
    // ---- stage embedding ----
    for (int i = tid; i < VV * HH; i += 256) emb_s[i] = emb[i];
    // ---- stage Wo with padded stride ----
    for (int i = tid; i < VV * HH; i += 256) {
        int v = i >> 7, k = i & (HH - 1);
        wo_s[v * RSTR + k] = Wo[i];
    }
    if (tid < VV) bys[tid] = b_y[tid];
    if (half == 0) hbuf[j] = hidden[(size_t)b * HH + j];
    const float bh = b_h[j];

    // ---- Wh slice into registers: wreg[kk] = Wh[j][half*64 + kk] ----
    float wreg[64];
    {
        const float4* wg = (const float4*)(Wh + (size_t)j * HH + half * 64);
        #pragma unroll
        for (int i = 0; i < 16; i++) {
            float4 t4 = wg[i];
            wreg[4*i+0] = t4.x; wreg[4*i+1] = t4.y;
            wreg[4*i+2] = t4.z; wreg[4*i+3] = t4.w;
        }
    }
    __syncthreads();

    int cur = 0;
    const int su = tid >> 3;   // burst: step-in-window (0..31)
    const int vg = tid & 7;    // burst: vocab group (v = vg + 8i)

    for (int t = 0; t < LL; ++t) {
        // ---- phase A: partial dot over my half of K ----
        const float4* h4 = (const float4*)(hbuf + cur * HH + half * 64);
        float4 a = {0.f, 0.f, 0.f, 0.f};
        float4 c = {0.f, 0.f, 0.f, 0.f};
        #pragma unroll
        for (int i = 0; i < 16; i += 2) {
            float4 h0 = h4[i];
            float4 h1 = h4[i + 1];
            a.x += wreg[4*i+0] * h0.x;  a.y += wreg[4*i+1] * h0.y;
            a.z += wreg[4*i+2] * h0.z;  a.w += wreg[4*i+3] * h0.w;
            c.x += wreg[4*i+4] * h1.x;  c.y += wreg[4*i+5] * h1.y;
            c.z += wreg[4*i+6] * h1.z;  c.w += wreg[4*i+7] * h1.w;
        }
        float acc = ((a.x + a.y) + (a.z + a.w)) + ((c.x + c.y) + (c.z + c.w));

        if (half) partial[j] = acc;
        __syncthreads();

        // ---- phase C: combine + tanh (half0 only) ----
        if (!half) {
            int idx = xbuf[t];
            float val = acc + partial[j] + emb_s[idx * HH + j] + bh;
            float hn = tanhf(val);
            hbuf[(cur ^ 1) * HH + j] = hn;
            ring[(t & (WIN - 1)) * RSTR + j] = hn;
        }
        __syncthreads();
        cur ^= 1;

        // ---- burst: logits for the completed 32-step window ----
        if ((t & (WIN - 1)) == (WIN - 1)) {
            const int base_t = t - (WIN - 1);
            float accl0 = 0.f, accl1 = 0.f, accl2 = 0.f, accl3 = 0.f, accl4 = 0.f;
            const float4* hr = (const float4*)(ring + su * RSTR);
            const float* w0 = wo_s + (vg +  0) * RSTR;
            const float* w1 = wo_s + (vg +  8) * RSTR;
            const float* w2 = wo_s + (vg + 16) * RSTR;
            const float* w3 = wo_s + (vg + 24) * RSTR;
            const float* w4 = wo_s + (vg + 32) * RSTR;
            #pragma unroll 8
            for (int kc = 0; kc < 32; kc++) {
                float4 hv = hr[kc];
                float4 v0 = *(const float4*)(w0 + kc * 4);
                float4 v1 = *(const float4*)(w1 + kc * 4);
                float4 v2 = *(const float4*)(w2 + kc * 4);
                float4 v3 = *(const float4*)(w3 + kc * 4);
                float4 v4 = *(const float4*)(w4 + kc * 4);
                accl0 += v0.x*hv.x + v0.y*hv.y + v0.z*hv.z + v0.w*hv.w;
                accl1 += v1.x*hv.x + v1.y*hv.y + v1.z*hv.z + v1.w*hv.w;
                accl2 += v2.x*hv.x + v2.y*hv.y + v2.z*hv.z + v2.w*hv.w;
                accl3 += v3.x*hv.x + v3.y*hv.y + v3.z*hv.z + v3.w*hv.w;
                accl4 += v4.x*hv.x + v4.y*hv.y + v4.z*hv.z + v4.w*hv.w;
            }
            float* outp = out + (size_t)b * LL * VV + (size_t)(base_t + su) * VV + vg;
            outp[ 0] = accl0 + bys[vg +  0];
            outp[ 8] = accl1 + bys[vg +  8];
            outp[16] = accl2 + bys[vg + 16];
            outp[24] = accl3 + bys[vg + 24];
            outp[32] = accl4 + bys[vg + 32];
            __syncthreads();   // protect ring before next window overwrites it
        }
    }

    // ---- final hidden: h_L is in hbuf[cur] (1024 toggles -> cur==0) ----
    if (!half) {
        out[(size_t)BB * LL * VV + (size_t)b * HH + j] = hbuf[cur * HH + j];
    }
}

extern "C" void kernel_launch(void* const* d_in, const int* in_sizes, int n_in,
                              void* d_out, int out_size, void* d_ws, size_t ws_size,
                              hipStream_t stream) {
    const int*   x      = (const int*)  d_in[0];
    const float* hidden = (const float*)d_in[1];
    const float* emb    = (const float*)d_in[2];
    const float* Wh     = (const float*)d_in[3];
    const float* Wo     = (const float*)d_in[4];
    const float* bh     = (const float*)d_in[5];
    const float* by     = (const float*)d_in[6];
    float*       out    = (float*)      d_out;

    rnn_fused<<<dim3(BB), dim3(256), 0, stream>>>(x, hidden, emb, Wh, Wo, bh, by, out);
}

// Round 2
// 703.427 us; speedup vs baseline: 1.1741x; 1.1741x over previous
//
#include <hip/hip_runtime.h>

// CharRNN fused kernel: B=256, L=1024, V=40, H=128.
// One block per batch row (grid 256 = 1 block/CU), 256 threads = 4 waves.
// R2: intra-wave split-K pairing (lane l <-> l^32 share output j, halves of K)
// combined via __shfl_xor -> ONE __syncthreads per step (was 2 + LDS partial).
// e_t prefetched a step ahead (b_h folded in at staging); fast tanh via
// v_exp_f32 + v_rcp_f32 instead of libm tanhf.

#define BB 256
#define LL 1024
#define VV 40
#define HH 128
#define WIN 32
#define RSTR 132   // padded stride: breaks power-of-2 bank patterns for ring/Wo

__device__ __forceinline__ float fast_tanh(float x) {
    // tanh(x) = 1 - 2/(exp(2x)+1); exp overflow -> inf -> rcp -> 0 -> +1 (correct)
    float e = __expf(2.0f * x);                  // v_mul + v_exp_f32
    float r = __builtin_amdgcn_rcpf(e + 1.0f);   // v_add + v_rcp_f32
    return 1.0f - 2.0f * r;                      // fma
}

__global__ __launch_bounds__(256) void rnn_fused(
    const int*   __restrict__ x,       // [B,L]
    const float* __restrict__ hidden,  // [B,H]
    const float* __restrict__ emb,     // [V,H]
    const float* __restrict__ Wh,      // [H,H]
    const float* __restrict__ Wo,      // [V,H]
    const float* __restrict__ b_h,     // [H]
    const float* __restrict__ b_y,     // [V]
    float*       __restrict__ out)     // [B*L*V logits][B*H final_hidden]
{
    __shared__ float emb_s[VV * HH];     // 20.0 KB  (b_h folded in)
    __shared__ float wo_s[VV * RSTR];    // 21.1 KB
    __shared__ float ring[WIN * RSTR];   // 16.9 KB
    __shared__ float hbuf[2 * HH];       //  1.0 KB
    __shared__ float bys[VV];
    __shared__ int   xbuf[LL];           //  4.0 KB
    // ~63.3 KB static LDS

    const int tid  = threadIdx.x;
    const int b    = blockIdx.x;
    const int w    = tid >> 6;          // wave 0..3
    const int l    = tid & 63;          // lane
    const int j    = (w << 5) + (l & 31);  // output index 0..127
    const int kh   = l >> 5;            // K-half 0/1 (pair partner = l^32)

    // ---- stage x sequence ----
    {
        const int4* xg = (const int4*)(x + (size_t)b * LL);
        int4* xs = (int4*)xbuf;
        for (int i = tid; i < LL / 4; i += 256) xs[i] = xg[i];
    }
    // ---- stage embedding with b_h folded in ----
    for (int i = tid; i < VV * HH; i += 256)
        emb_s[i] = emb[i] + b_h[i & (HH - 1)];
    // ---- stage Wo with padded stride ----
    for (int i = tid; i < VV * HH; i += 256) {
        int v = i >> 7, k = i & (HH - 1);
        wo_s[v * RSTR + k] = Wo[i];
    }
    if (tid < VV) bys[tid] = b_y[tid];
    if (tid < HH) hbuf[tid] = hidden[(size_t)b * HH + tid];

    // ---- Wh slice into registers: wreg[kk] = Wh[j][kh*64 + kk] ----
    float wreg[64];
    {
        const float4* wg = (const float4*)(Wh + (size_t)j * HH + (kh << 6));
        #pragma unroll
        for (int i = 0; i < 16; i++) {
            float4 t4 = wg[i];
            wreg[4*i+0] = t4.x; wreg[4*i+1] = t4.y;
            wreg[4*i+2] = t4.z; wreg[4*i+3] = t4.w;
        }
    }
    __syncthreads();

    int cur = 0;
    const int su = tid >> 3;   // burst: step-in-window (0..31)
    const int vg = tid & 7;    // burst: vocab group (v = vg + 8i)

    // e-prefetch pipeline: e_cur = e(x[t]) (+b_h), idx_next = x[t+1]
    float e_cur   = emb_s[xbuf[0] * HH + j];
    int   idx_next = xbuf[1];
    float hn = 0.f;

    for (int t = 0; t < LL; ++t) {
        const float4* h4 = (const float4*)(hbuf + cur * HH + (kh << 6));

        // prefetch e for step t+1 (independent of h -> overlaps the dot)
        float e_next = emb_s[idx_next * HH + j];
        int t2 = t + 2;
        idx_next = xbuf[t2 < LL ? t2 : (LL - 1)];

        // ---- split-K dot over my 64-wide half ----
        float4 a = {0.f, 0.f, 0.f, 0.f};
        float4 c = {0.f, 0.f, 0.f, 0.f};
        #pragma unroll
        for (int i = 0; i < 16; i += 2) {
            float4 h0 = h4[i];
            float4 h1 = h4[i + 1];
            a.x += wreg[4*i+0] * h0.x;  a.y += wreg[4*i+1] * h0.y;
            a.z += wreg[4*i+2] * h0.z;  a.w += wreg[4*i+3] * h0.w;
            c.x += wreg[4*i+4] * h1.x;  c.y += wreg[4*i+5] * h1.y;
            c.z += wreg[4*i+6] * h1.z;  c.w += wreg[4*i+7] * h1.w;
        }
        float acc = ((a.x + a.y) + (a.z + a.w)) + ((c.x + c.y) + (c.z + c.w));
        acc += __shfl_xor(acc, 32, 64);   // combine K-halves within the wave

        float val = acc + e_cur;          // e_cur already includes b_h
        hn = fast_tanh(val);
        if (kh == 0) {
            hbuf[(cur ^ 1) * HH + j] = hn;
            ring[(t & (WIN - 1)) * RSTR + j] = hn;
        }
        e_cur = e_next;
        __syncthreads();                  // the ONE barrier per step
        cur ^= 1;

        // ---- burst: logits for the completed 32-step window ----
        if ((t & (WIN - 1)) == (WIN - 1)) {
            const int base_t = t - (WIN - 1);
            float accl0 = 0.f, accl1 = 0.f, accl2 = 0.f, accl3 = 0.f, accl4 = 0.f;
            const float4* hr = (const float4*)(ring + su * RSTR);
            const float* w0 = wo_s + (vg +  0) * RSTR;
            const float* w1 = wo_s + (vg +  8) * RSTR;
            const float* w2 = wo_s + (vg + 16) * RSTR;
            const float* w3 = wo_s + (vg + 24) * RSTR;
            const float* w4 = wo_s + (vg + 32) * RSTR;
            #pragma unroll 8
            for (int kc = 0; kc < 32; kc++) {
                float4 hv = hr[kc];
                float4 v0 = *(const float4*)(w0 + kc * 4);
                float4 v1 = *(const float4*)(w1 + kc * 4);
                float4 v2 = *(const float4*)(w2 + kc * 4);
                float4 v3 = *(const float4*)(w3 + kc * 4);
                float4 v4 = *(const float4*)(w4 + kc * 4);
                accl0 += v0.x*hv.x + v0.y*hv.y + v0.z*hv.z + v0.w*hv.w;
                accl1 += v1.x*hv.x + v1.y*hv.y + v1.z*hv.z + v1.w*hv.w;
                accl2 += v2.x*hv.x + v2.y*hv.y + v2.z*hv.z + v2.w*hv.w;
                accl3 += v3.x*hv.x + v3.y*hv.y + v3.z*hv.z + v3.w*hv.w;
                accl4 += v4.x*hv.x + v4.y*hv.y + v4.z*hv.z + v4.w*hv.w;
            }
            float* outp = out + (size_t)b * LL * VV + (size_t)(base_t + su) * VV + vg;
            outp[ 0] = accl0 + bys[vg +  0];
            outp[ 8] = accl1 + bys[vg +  8];
            outp[16] = accl2 + bys[vg + 16];
            outp[24] = accl3 + bys[vg + 24];
            outp[32] = accl4 + bys[vg + 32];
            __syncthreads();   // ring must be fully read before next window overwrites
        }
    }

    // ---- final hidden: kh==0 lanes still hold h_{L} from the last step ----
    if (kh == 0) {
        out[(size_t)BB * LL * VV + (size_t)b * HH + j] = hn;
    }
}

extern "C" void kernel_launch(void* const* d_in, const int* in_sizes, int n_in,
                              void* d_out, int out_size, void* d_ws, size_t ws_size,
                              hipStream_t stream) {
    const int*   x      = (const int*)  d_in[0];
    const float* hidden = (const float*)d_in[1];
    const float* emb    = (const float*)d_in[2];
    const float* Wh     = (const float*)d_in[3];
    const float* Wo     = (const float*)d_in[4];
    const float* bh     = (const float*)d_in[5];
    const float* by     = (const float*)d_in[6];
    float*       out    = (float*)      d_out;

    rnn_fused<<<dim3(BB), dim3(256), 0, stream>>>(x, hidden, emb, Wh, Wo, bh, by, out);
}

// Round 3
// 587.902 us; speedup vs baseline: 1.4048x; 1.1965x over previous
//
#include <hip/hip_runtime.h>

// CharRNN fused: B=256, L=1024, V=40, H=128. One block/CU, 256 thr = 4 waves.
// R3: wave w OWNS h-quarter Q_w=[32w,32w+32) in registers (lane k'<32 holds
// h[32w+k']). Per step each wave computes partial dots over its own quarter
// for ALL j via v_readlane broadcasts (VALU, not LDS). Cross-wave K-reduce
// through a tiny LDS partial buffer (2 writes + 4 reads per wave/step).
// Logits piggyback on the same broadcasts (lane v<40 holds Wo[v][Q_w] in
// regs); per-wave logit partials go to LDS, reduced+stored every 32 steps.

#define BB 256
#define LL 1024
#define VV 40
#define HH 128
#define WIN 32

__device__ __forceinline__ float fast_tanh(float x) {
    // tanh(x) = 1 - 2/(exp(2x)+1); overflow -> inf -> rcp -> 0 -> +1 (correct)
    float e = __expf(2.0f * x);
    float r = __builtin_amdgcn_rcpf(e + 1.0f);
    return 1.0f - 2.0f * r;
}

__device__ __forceinline__ float bcast(float v, int k) {
    return __int_as_float(__builtin_amdgcn_readlane(__float_as_int(v), k));
}

__global__ __launch_bounds__(256) void rnn_fused(
    const int*   __restrict__ x,       // [B,L]
    const float* __restrict__ hidden,  // [B,H]
    const float* __restrict__ emb,     // [V,H]
    const float* __restrict__ Wh,      // [H,H]
    const float* __restrict__ Wo,      // [V,H]
    const float* __restrict__ b_h,     // [H]
    const float* __restrict__ b_y,     // [V]
    float*       __restrict__ out)     // [B*L*V logits][B*H final_hidden]
{
    __shared__ float emb_s[VV * HH];        // 20 KB (b_h folded in)
    __shared__ float part[2][4][HH];        //  4 KB  main-dot partials (dbuf)
    __shared__ float lpart[WIN][4][48];     // 24 KB  logit partials (pad 40->48)
    __shared__ float bys[VV];
    __shared__ int   xbuf[LL];              //  4 KB
    // ~53.4 KB static LDS

    const int tid  = threadIdx.x;
    const int b    = blockIdx.x;
    const int w    = tid >> 6;          // wave 0..3
    const int lane = tid & 63;
    const int kq   = w << 5;            // wave's k/j quarter base

    // ---- stage x, embedding(+b_h), b_y ----
    {
        const int4* xg = (const int4*)(x + (size_t)b * LL);
        int4* xs = (int4*)xbuf;
        for (int i = tid; i < LL / 4; i += 256) xs[i] = xg[i];
    }
    for (int i = tid; i < VV * HH; i += 256)
        emb_s[i] = emb[i] + b_h[i & (HH - 1)];
    if (tid < VV) bys[tid] = b_y[tid];

    // ---- weights into registers ----
    // wreg0[k] = Wh[lane][kq+k], wreg1[k] = Wh[lane+64][kq+k],
    // woreg[k] = Wo[min(lane,39)][kq+k]
    float wreg0[32], wreg1[32], woreg[32];
    {
        const float4* p0 = (const float4*)(Wh + (size_t)lane * HH + kq);
        const float4* p1 = (const float4*)(Wh + (size_t)(lane + 64) * HH + kq);
        int vrow = (lane < VV) ? lane : 0;
        const float4* p2 = (const float4*)(Wo + (size_t)vrow * HH + kq);
        #pragma unroll
        for (int i = 0; i < 8; i++) {
            float4 a = p0[i], c = p1[i], d = p2[i];
            wreg0[4*i+0] = a.x; wreg0[4*i+1] = a.y; wreg0[4*i+2] = a.z; wreg0[4*i+3] = a.w;
            wreg1[4*i+0] = c.x; wreg1[4*i+1] = c.y; wreg1[4*i+2] = c.z; wreg1[4*i+3] = c.w;
            woreg[4*i+0] = d.x; woreg[4*i+1] = d.y; woreg[4*i+2] = d.z; woreg[4*i+3] = d.w;
        }
    }
    float hreg = 0.f;
    if (lane < 32) hreg = hidden[(size_t)b * HH + kq + lane];
    __syncthreads();

    int p = 0;
    int idx_cur = xbuf[0];

    for (int t = 0; t < LL; ++t) {
        // e for THIS step (issued early; ~200cy of k-loop hides the latency)
        float e_cur = 0.f;
        if (lane < 32) e_cur = emb_s[idx_cur * HH + kq + lane];
        int tn = t + 1; if (tn > LL - 1) tn = LL - 1;
        int idx_next = xbuf[tn];

        // ---- broadcast k-loop: partials over my wave's k-quarter ----
        float acc0 = 0.f, acc1 = 0.f, lacc = 0.f;
        #pragma unroll
        for (int k = 0; k < 32; ++k) {
            float s = bcast(hreg, k);          // h_{t-1}[kq+k], VALU broadcast
            acc0 = fmaf(s, wreg0[k], acc0);    // j = lane
            acc1 = fmaf(s, wreg1[k], acc1);    // j = lane+64
            lacc = fmaf(s, woreg[k], lacc);    // v = lane (<40)
        }

        part[p][w][lane]      = acc0;
        part[p][w][lane + 64] = acc1;
        if (t != 0 && lane < VV) lpart[(t - 1) & (WIN - 1)][w][lane] = lacc;
        __syncthreads();

        // ---- burst: reduce+store logit rows [t-32, t) ----
        if (t >= WIN && (t & (WIN - 1)) == 0) {
            const int rbase = t - WIN;
            #pragma unroll
            for (int q = 0; q < 5; ++q) {
                int o  = tid + 256 * q;        // 0..1279
                int tp = o / 40;
                int v  = o - 40 * tp;
                float sm = lpart[tp][0][v] + lpart[tp][1][v]
                         + lpart[tp][2][v] + lpart[tp][3][v] + bys[v];
                out[(size_t)b * LL * VV + (size_t)(rbase + tp) * VV + v] = sm;
            }
            __syncthreads();   // next step's lpart[0] write must wait
        }

        // ---- K-reduction + tanh: my wave's j-quarter only ----
        if (lane < 32) {
            int j = kq + lane;
            float vsum = part[p][0][j] + part[p][1][j]
                       + part[p][2][j] + part[p][3][j];
            hreg = fast_tanh(vsum + e_cur);
        }
        idx_cur = idx_next;
        p ^= 1;
    }

    // ---- epilogue: logits for row L-1 from final h, then last burst ----
    {
        float lacc = 0.f;
        #pragma unroll
        for (int k = 0; k < 32; ++k) {
            float s = bcast(hreg, k);
            lacc = fmaf(s, woreg[k], lacc);
        }
        if (lane < VV) lpart[(LL - 1) & (WIN - 1)][w][lane] = lacc;
        __syncthreads();
        const int rbase = LL - WIN;
        #pragma unroll
        for (int q = 0; q < 5; ++q) {
            int o  = tid + 256 * q;
            int tp = o / 40;
            int v  = o - 40 * tp;
            float sm = lpart[tp][0][v] + lpart[tp][1][v]
                     + lpart[tp][2][v] + lpart[tp][3][v] + bys[v];
            out[(size_t)b * LL * VV + (size_t)(rbase + tp) * VV + v] = sm;
        }
        // final hidden
        if (lane < 32)
            out[(size_t)BB * LL * VV + (size_t)b * HH + kq + lane] = hreg;
    }
}

extern "C" void kernel_launch(void* const* d_in, const int* in_sizes, int n_in,
                              void* d_out, int out_size, void* d_ws, size_t ws_size,
                              hipStream_t stream) {
    const int*   x      = (const int*)  d_in[0];
    const float* hidden = (const float*)d_in[1];
    const float* emb    = (const float*)d_in[2];
    const float* Wh     = (const float*)d_in[3];
    const float* Wo     = (const float*)d_in[4];
    const float* bh     = (const float*)d_in[5];
    const float* by     = (const float*)d_in[6];
    float*       out    = (float*)      d_out;

    rnn_fused<<<dim3(BB), dim3(256), 0, stream>>>(x, hidden, emb, Wh, Wo, bh, by, out);
}

// Round 4
// 587.133 us; speedup vs baseline: 1.4066x; 1.0013x over previous
//
#include <hip/hip_runtime.h>

// CharRNN fused: B=256, L=1024, V=40, H=128. One block/CU, 256 thr = 4 waves.
// R3 structure: wave w OWNS h-quarter Q_w=[32w,32w+32) in registers (lane k'<32
// holds h[32w+k']). Per step each wave computes partial dots over its own
// quarter for ALL j via v_readlane broadcasts (VALU, not LDS). Cross-wave
// K-reduce through a tiny LDS partial buffer. Logits piggyback on the same
// broadcasts; per-wave logit partials -> LDS, reduced+stored every 32 steps.
//
// R4: __launch_bounds__(256, 1). We run 1 wave/SIMD (grid = 1 block/CU), so
// min-waves=1 raises the VGPR budget to ~512 and keeps the 96 weight floats
// in architectural VGPRs. R3's VGPR_Count=80 < 96 proved the compiler had
// pushed them to AGPRs, adding a v_accvgpr_read before nearly every FMA
// (~2x VALU issue on the critical serial chain).

#define BB 256
#define LL 1024
#define VV 40
#define HH 128
#define WIN 32

__device__ __forceinline__ float fast_tanh(float x) {
    // tanh(x) = 1 - 2/(exp(2x)+1); overflow -> inf -> rcp -> 0 -> +1 (correct)
    float e = __expf(2.0f * x);
    float r = __builtin_amdgcn_rcpf(e + 1.0f);
    return 1.0f - 2.0f * r;
}

__device__ __forceinline__ float bcast(float v, int k) {
    return __int_as_float(__builtin_amdgcn_readlane(__float_as_int(v), k));
}

__global__ __launch_bounds__(256, 1) void rnn_fused(
    const int*   __restrict__ x,       // [B,L]
    const float* __restrict__ hidden,  // [B,H]
    const float* __restrict__ emb,     // [V,H]
    const float* __restrict__ Wh,      // [H,H]
    const float* __restrict__ Wo,      // [V,H]
    const float* __restrict__ b_h,     // [H]
    const float* __restrict__ b_y,     // [V]
    float*       __restrict__ out)     // [B*L*V logits][B*H final_hidden]
{
    __shared__ float emb_s[VV * HH];        // 20 KB (b_h folded in)
    __shared__ float part[2][4][HH];        //  4 KB  main-dot partials (dbuf)
    __shared__ float lpart[WIN][4][48];     // 24 KB  logit partials (pad 40->48)
    __shared__ float bys[VV];
    __shared__ int   xbuf[LL];              //  4 KB
    // ~53.4 KB static LDS

    const int tid  = threadIdx.x;
    const int b    = blockIdx.x;
    const int w    = tid >> 6;          // wave 0..3
    const int lane = tid & 63;
    const int kq   = w << 5;            // wave's k/j quarter base

    // ---- stage x, embedding(+b_h), b_y ----
    {
        const int4* xg = (const int4*)(x + (size_t)b * LL);
        int4* xs = (int4*)xbuf;
        for (int i = tid; i < LL / 4; i += 256) xs[i] = xg[i];
    }
    for (int i = tid; i < VV * HH; i += 256)
        emb_s[i] = emb[i] + b_h[i & (HH - 1)];
    if (tid < VV) bys[tid] = b_y[tid];

    // ---- weights into registers ----
    // wreg0[k] = Wh[lane][kq+k], wreg1[k] = Wh[lane+64][kq+k],
    // woreg[k] = Wo[min(lane,39)][kq+k]
    float wreg0[32], wreg1[32], woreg[32];
    {
        const float4* p0 = (const float4*)(Wh + (size_t)lane * HH + kq);
        const float4* p1 = (const float4*)(Wh + (size_t)(lane + 64) * HH + kq);
        int vrow = (lane < VV) ? lane : 0;
        const float4* p2 = (const float4*)(Wo + (size_t)vrow * HH + kq);
        #pragma unroll
        for (int i = 0; i < 8; i++) {
            float4 a = p0[i], c = p1[i], d = p2[i];
            wreg0[4*i+0] = a.x; wreg0[4*i+1] = a.y; wreg0[4*i+2] = a.z; wreg0[4*i+3] = a.w;
            wreg1[4*i+0] = c.x; wreg1[4*i+1] = c.y; wreg1[4*i+2] = c.z; wreg1[4*i+3] = c.w;
            woreg[4*i+0] = d.x; woreg[4*i+1] = d.y; woreg[4*i+2] = d.z; woreg[4*i+3] = d.w;
        }
    }
    float hreg = 0.f;
    if (lane < 32) hreg = hidden[(size_t)b * HH + kq + lane];
    __syncthreads();

    int p = 0;
    int idx_cur = xbuf[0];

    for (int t = 0; t < LL; ++t) {
        // e for THIS step (issued early; k-loop hides the LDS latency)
        float e_cur = 0.f;
        if (lane < 32) e_cur = emb_s[idx_cur * HH + kq + lane];
        int tn = t + 1; if (tn > LL - 1) tn = LL - 1;
        int idx_next = xbuf[tn];

        // ---- broadcast k-loop: partials over my wave's k-quarter ----
        float acc0 = 0.f, acc1 = 0.f, lacc = 0.f;
        #pragma unroll
        for (int k = 0; k < 32; ++k) {
            float s = bcast(hreg, k);          // h_{t-1}[kq+k], VALU broadcast
            acc0 = fmaf(s, wreg0[k], acc0);    // j = lane
            acc1 = fmaf(s, wreg1[k], acc1);    // j = lane+64
            lacc = fmaf(s, woreg[k], lacc);    // v = lane (<40)
        }

        part[p][w][lane]      = acc0;
        part[p][w][lane + 64] = acc1;
        if (t != 0 && lane < VV) lpart[(t - 1) & (WIN - 1)][w][lane] = lacc;
        __syncthreads();

        // ---- burst: reduce+store logit rows [t-32, t) ----
        if (t >= WIN && (t & (WIN - 1)) == 0) {
            const int rbase = t - WIN;
            #pragma unroll
            for (int q = 0; q < 5; ++q) {
                int o  = tid + 256 * q;        // 0..1279
                int tp = o / 40;
                int v  = o - 40 * tp;
                float sm = lpart[tp][0][v] + lpart[tp][1][v]
                         + lpart[tp][2][v] + lpart[tp][3][v] + bys[v];
                out[(size_t)b * LL * VV + (size_t)(rbase + tp) * VV + v] = sm;
            }
            __syncthreads();   // next step's lpart[0] write must wait
        }

        // ---- K-reduction + tanh: my wave's j-quarter only ----
        if (lane < 32) {
            int j = kq + lane;
            float vsum = part[p][0][j] + part[p][1][j]
                       + part[p][2][j] + part[p][3][j];
            hreg = fast_tanh(vsum + e_cur);
        }
        idx_cur = idx_next;
        p ^= 1;
    }

    // ---- epilogue: logits for row L-1 from final h, then last burst ----
    {
        float lacc = 0.f;
        #pragma unroll
        for (int k = 0; k < 32; ++k) {
            float s = bcast(hreg, k);
            lacc = fmaf(s, woreg[k], lacc);
        }
        if (lane < VV) lpart[(LL - 1) & (WIN - 1)][w][lane] = lacc;
        __syncthreads();
        const int rbase = LL - WIN;
        #pragma unroll
        for (int q = 0; q < 5; ++q) {
            int o  = tid + 256 * q;
            int tp = o / 40;
            int v  = o - 40 * tp;
            float sm = lpart[tp][0][v] + lpart[tp][1][v]
                     + lpart[tp][2][v] + lpart[tp][3][v] + bys[v];
            out[(size_t)b * LL * VV + (size_t)(rbase + tp) * VV + v] = sm;
        }
        // final hidden
        if (lane < 32)
            out[(size_t)BB * LL * VV + (size_t)b * HH + kq + lane] = hreg;
    }
}

extern "C" void kernel_launch(void* const* d_in, const int* in_sizes, int n_in,
                              void* d_out, int out_size, void* d_ws, size_t ws_size,
                              hipStream_t stream) {
    const int*   x      = (const int*)  d_in[0];
    const float* hidden = (const float*)d_in[1];
    const float* emb    = (const float*)d_in[2];
    const float* Wh     = (const float*)d_in[3];
    const float* Wo     = (const float*)d_in[4];
    const float* bh     = (const float*)d_in[5];
    const float* by     = (const float*)d_in[6];
    float*       out    = (float*)      d_out;

    rnn_fused<<<dim3(BB), dim3(256), 0, stream>>>(x, hidden, emb, Wh, Wo, bh, by, out);
}